// Round 1
// baseline (244.523 us; speedup 1.0000x reference)
//
#include <hip/hip_runtime.h>
#include <math.h>

#define NFM_B 16384
#define NFM_F 39
#define NFM_E 16
#define NFM_H 200
#define TR    32   // rows per block

// Dense layer: hout[r][j] = relu(b[j] + sum_k hin[r][k] * W[k][j])
// Thread mapping: wave = one r-group of 8 rows; lane jl=tid&63 covers
// j = jl, jl+64, jl+128, jl+192(<200). h-reads are wave-uniform -> LDS
// broadcast (free); W reads lane-consecutive -> coalesced L2 hits.
template<int K, int INSTRIDE>
__device__ __forceinline__ void dense_relu_layer(
    const float* __restrict__ hin,   // [TR][INSTRIDE] (LDS)
    const float* __restrict__ Wg,    // [K][NFM_H]     (global, L2-resident)
    const float* __restrict__ bvec,  // [NFM_H]        (global)
    float* __restrict__ hout,        // [TR][NFM_H]    (LDS)
    int tid)
{
    const int jl = tid & 63;
    const int rb = (tid >> 6) * 8;   // 4 waves -> 4 r-groups of 8 rows

    float acc[4][8];
#pragma unroll
    for (int a = 0; a < 4; ++a)
#pragma unroll
        for (int rr = 0; rr < 8; ++rr) acc[a][rr] = 0.f;

    for (int k = 0; k < K; ++k) {
        float hv[8];
#pragma unroll
        for (int rr = 0; rr < 8; ++rr)
            hv[rr] = hin[(rb + rr) * INSTRIDE + k];   // broadcast across wave
        float wv[4];
#pragma unroll
        for (int a = 0; a < 4; ++a) {
            int j = jl + 64 * a;
            wv[a] = (j < NFM_H) ? Wg[k * NFM_H + j] : 0.f;
        }
#pragma unroll
        for (int a = 0; a < 4; ++a)
#pragma unroll
            for (int rr = 0; rr < 8; ++rr)
                acc[a][rr] += hv[rr] * wv[a];
    }

#pragma unroll
    for (int a = 0; a < 4; ++a) {
        int j = jl + 64 * a;
        if (j < NFM_H) {
            float bj = bvec[j];
#pragma unroll
            for (int rr = 0; rr < 8; ++rr)
                hout[(rb + rr) * NFM_H + j] = fmaxf(acc[a][rr] + bj, 0.f);
        }
    }
}

__global__ __launch_bounds__(256, 2)
void nfm_fused_kernel(
    const int*   __restrict__ feat_ids,   // [B,F]
    const float* __restrict__ feat_vals,  // [B,F]
    const float* __restrict__ w,          // [VOCAB,1]
    const float* __restrict__ v,          // [VOCAB,E]
    const float* __restrict__ bglob,      // [1]
    const float* __restrict__ w0, const float* __restrict__ b0,  // [16,200],[200]
    const float* __restrict__ w1, const float* __restrict__ b1,  // [200,200],[200]
    const float* __restrict__ w2, const float* __restrict__ b2,  // [200,200],[200]
    float* __restrict__ out)              // [B]
{
    __shared__ float hA[TR][NFM_H];       // ping  (51.2 KB total for both)
    __shared__ float hB[TR][NFM_H];       // pong
    __shared__ float fmS[TR][NFM_E];
    __shared__ float lrS[TR];

    const int tid  = threadIdx.x;
    const int row0 = blockIdx.x * TR;

    // ---------- Phase 1: embedding gather + FM pooling + LR ----------
    // 16 lanes per row (one per embedding dim), 16 rows per pass, 2 passes.
    {
        const int lane_e = tid & 15;
        const int rsub   = tid >> 4;      // 0..15
        for (int pass = 0; pass < 2; ++pass) {
            const int rl = pass * 16 + rsub;
            const int r  = row0 + rl;
            const int*   ids  = feat_ids  + r * NFM_F;
            const float* vals = feat_vals + r * NFM_F;

            float xv = 0.f, x2v2 = 0.f;
            for (int f = 0; f < NFM_F; ++f) {
                int   id  = ids[f];
                float val = vals[f];
                float ve  = v[id * NFM_E + lane_e];  // 16 lanes -> 64B coalesced
                float t   = val * ve;
                xv   += t;
                x2v2 += t * t;
            }
            fmS[rl][lane_e] = 0.5f * (xv * xv - x2v2);

            // LR: lane e handles fields f = e, e+16, e+32; reduce over 16 lanes
            float lr = 0.f;
            for (int f = lane_e; f < NFM_F; f += 16)
                lr += vals[f] * w[ids[f]];
#pragma unroll
            for (int off = 8; off >= 1; off >>= 1)
                lr += __shfl_xor(lr, off, 16);
            if (lane_e == 0) lrS[rl] = lr;
        }
    }
    __syncthreads();

    // ---------- MLP: 16 -> 200 -> 200 -> 200, relu each ----------
    dense_relu_layer<NFM_E, NFM_E>(&fmS[0][0], w0, b0, &hA[0][0], tid);
    __syncthreads();
    dense_relu_layer<NFM_H, NFM_H>(&hA[0][0],  w1, b1, &hB[0][0], tid);
    __syncthreads();
    dense_relu_layer<NFM_H, NFM_H>(&hB[0][0],  w2, b2, &hA[0][0], tid);
    __syncthreads();

    // ---------- Epilogue: row-sum + lr + bias -> sigmoid ----------
    {
        const int r = tid >> 3;           // 32 rows
        const int q = tid & 7;            // 8 partials of 25 elements
        float s = 0.f;
        const int j0 = q * 25;
#pragma unroll
        for (int i = 0; i < 25; ++i) s += hA[r][j0 + i];
#pragma unroll
        for (int off = 4; off >= 1; off >>= 1)
            s += __shfl_xor(s, off, 8);
        if (q == 0) {
            float logit = lrS[r] + bglob[0] + s;
            out[row0 + r] = 1.f / (1.f + expf(-logit));
        }
    }
}

extern "C" void kernel_launch(void* const* d_in, const int* in_sizes, int n_in,
                              void* d_out, int out_size, void* d_ws, size_t ws_size,
                              hipStream_t stream) {
    const int*   feat_ids  = (const int*)  d_in[0];
    const float* feat_vals = (const float*)d_in[1];
    const float* w   = (const float*)d_in[2];
    const float* v   = (const float*)d_in[3];
    const float* b   = (const float*)d_in[4];
    const float* w0  = (const float*)d_in[5];
    const float* b0  = (const float*)d_in[6];
    const float* w1  = (const float*)d_in[7];
    const float* b1  = (const float*)d_in[8];
    const float* w2  = (const float*)d_in[9];
    const float* b2  = (const float*)d_in[10];
    float* out = (float*)d_out;

    dim3 grid(NFM_B / TR);   // 512 blocks
    dim3 block(256);
    hipLaunchKernelGGL(nfm_fused_kernel, grid, block, 0, stream,
                       feat_ids, feat_vals, w, v, b,
                       w0, b0, w1, b1, w2, b2, out);
}

// Round 2
// 172.870 us; speedup vs baseline: 1.4145x; 1.4145x over previous
//
#include <hip/hip_runtime.h>
#include <math.h>

#define NFM_B 16384
#define NFM_F 39
#define NFM_E 16
#define NFM_H 200
#define TR    32   // rows per block

// Dense layer: hout[r][j] = relu(b[j] + sum_k hin[r][k] * W[k][j])
// Wave = one r-group of 8 rows. Lane jl (0..49 active) handles the four
// consecutive outputs j = 4*jl .. 4*jl+3, so W reads and hout writes are
// float4 (global_load_dwordx4 / ds_write_b128). k processed in chunks of 4
// so hin reads are ds_read_b128 (wave-broadcast -> conflict-free).
template<int K, int INSTRIDE>
__device__ __forceinline__ void dense_relu_layer(
    const float* __restrict__ hin,   // [TR][INSTRIDE] (LDS)
    const float* __restrict__ Wg,    // [K][NFM_H]     (global, L2-resident)
    const float* __restrict__ bvec,  // [NFM_H]        (global)
    float* __restrict__ hout,        // [TR][NFM_H]    (LDS)
    int tid)
{
    const int jl  = tid & 63;
    const int rb  = (tid >> 6) * 8;          // 4 waves -> 4 r-groups of 8 rows
    const int j4  = jl * 4;
    const bool act = (j4 < NFM_H);           // lanes 0..49 produce outputs
    const int j4c = act ? j4 : (NFM_H - 4);  // clamp so loads stay in-bounds

    float acc[4][8];
#pragma unroll
    for (int a = 0; a < 4; ++a)
#pragma unroll
        for (int rr = 0; rr < 8; ++rr) acc[a][rr] = 0.f;

    for (int kc = 0; kc < K / 4; ++kc) {
        const int k0 = kc * 4;
        float4 hv[8];
#pragma unroll
        for (int rr = 0; rr < 8; ++rr)
            hv[rr] = *(const float4*)&hin[(rb + rr) * INSTRIDE + k0];
        float4 wv[4];
#pragma unroll
        for (int kk = 0; kk < 4; ++kk)
            wv[kk] = *(const float4*)&Wg[(k0 + kk) * NFM_H + j4c];
#pragma unroll
        for (int kk = 0; kk < 4; ++kk) {
#pragma unroll
            for (int rr = 0; rr < 8; ++rr) {
                const float h = (&hv[rr].x)[kk];
                acc[0][rr] = fmaf(h, wv[kk].x, acc[0][rr]);
                acc[1][rr] = fmaf(h, wv[kk].y, acc[1][rr]);
                acc[2][rr] = fmaf(h, wv[kk].z, acc[2][rr]);
                acc[3][rr] = fmaf(h, wv[kk].w, acc[3][rr]);
            }
        }
    }

    const float4 bj = *(const float4*)&bvec[j4c];
    if (act) {
#pragma unroll
        for (int rr = 0; rr < 8; ++rr) {
            float4 o;
            o.x = fmaxf(acc[0][rr] + bj.x, 0.f);
            o.y = fmaxf(acc[1][rr] + bj.y, 0.f);
            o.z = fmaxf(acc[2][rr] + bj.z, 0.f);
            o.w = fmaxf(acc[3][rr] + bj.w, 0.f);
            *(float4*)&hout[(rb + rr) * NFM_H + j4] = o;
        }
    }
}

__global__ __launch_bounds__(256, 3)
void nfm_fused_kernel(
    const int*   __restrict__ feat_ids,   // [B,F]
    const float* __restrict__ feat_vals,  // [B,F]
    const float* __restrict__ w,          // [VOCAB,1]
    const float* __restrict__ v,          // [VOCAB,E]
    const float* __restrict__ bglob,      // [1]
    const float* __restrict__ w0, const float* __restrict__ b0,  // [16,200],[200]
    const float* __restrict__ w1, const float* __restrict__ b1,  // [200,200],[200]
    const float* __restrict__ w2, const float* __restrict__ b2,  // [200,200],[200]
    float* __restrict__ out)              // [B]
{
    // LDS: 25.6 + 25.6 + 0.13 KB = 51.3 KB -> 3 blocks/CU (was 53.8 -> 2)
    __shared__ __attribute__((aligned(16))) float hA[TR * NFM_H];
    __shared__ __attribute__((aligned(16))) float hB[TR * NFM_H];
    __shared__ float lrS[TR];
    // Aliased regions:
    //   phase 1 stages ids/vals in hA (dead until layer0 writes it)
    //   fm lives at the start of hB (dead once layer1 writes hB)
    int*   idsS  = (int*)hA;                      // [TR*F] = 1248 ints
    float* valsS = hA + TR * NFM_F;               // [TR*F] = 1248 floats
    float* fmS   = hB;                            // [TR][E]

    const int tid  = threadIdx.x;
    const int row0 = blockIdx.x * TR;

    // ---------- Phase 0: stage ids/vals (coalesced) ----------
    for (int i = tid; i < TR * NFM_F; i += 256) {
        idsS[i]  = feat_ids [row0 * NFM_F + i];
        valsS[i] = feat_vals[row0 * NFM_F + i];
    }
    __syncthreads();

    // ---------- Phase 1: embedding gather + FM pooling + LR ----------
    // 16 lanes per row (one per embedding dim), 16 rows per pass, 2 passes.
    {
        const int lane_e = tid & 15;
        const int rsub   = tid >> 4;      // 0..15
#pragma unroll
        for (int pass = 0; pass < 2; ++pass) {
            const int rl = pass * 16 + rsub;
            const int*   ids  = idsS  + rl * NFM_F;
            const float* vals = valsS + rl * NFM_F;

            float xv = 0.f, x2v2 = 0.f;
            for (int f = 0; f < NFM_F; ++f) {
                float ve = v[ids[f] * NFM_E + lane_e]; // 16 lanes -> 64B coalesced
                float t  = vals[f] * ve;
                xv   += t;
                x2v2 += t * t;
            }
            fmS[rl * NFM_E + lane_e] = 0.5f * (xv * xv - x2v2);

            // LR: lane e handles fields f = e, e+16, e+32; reduce over 16 lanes
            float lr = 0.f;
            for (int f = lane_e; f < NFM_F; f += 16)
                lr += vals[f] * w[ids[f]];
#pragma unroll
            for (int off = 8; off >= 1; off >>= 1)
                lr += __shfl_xor(lr, off, 16);
            if (lane_e == 0) lrS[rl] = lr;
        }
    }
    __syncthreads();

    // ---------- MLP: 16 -> 200 -> 200 -> 200, relu each ----------
    dense_relu_layer<NFM_E, NFM_E>(fmS, w0, b0, hA, tid);  // reads hB-alias, writes hA
    __syncthreads();
    dense_relu_layer<NFM_H, NFM_H>(hA, w1, b1, hB, tid);   // fm dead, hB reused
    __syncthreads();
    dense_relu_layer<NFM_H, NFM_H>(hB, w2, b2, hA, tid);
    __syncthreads();

    // ---------- Epilogue: row-sum + lr + bias -> sigmoid ----------
    {
        const int r = tid >> 3;           // 32 rows
        const int q = tid & 7;            // 8 partials of 25 elements
        float s = 0.f;
        const int j0 = q * 25;
#pragma unroll
        for (int i = 0; i < 25; ++i) s += hA[r * NFM_H + j0 + i];
#pragma unroll
        for (int off = 4; off >= 1; off >>= 1)
            s += __shfl_xor(s, off, 8);
        if (q == 0) {
            float logit = lrS[r] + bglob[0] + s;
            out[row0 + r] = 1.f / (1.f + expf(-logit));
        }
    }
}

extern "C" void kernel_launch(void* const* d_in, const int* in_sizes, int n_in,
                              void* d_out, int out_size, void* d_ws, size_t ws_size,
                              hipStream_t stream) {
    const int*   feat_ids  = (const int*)  d_in[0];
    const float* feat_vals = (const float*)d_in[1];
    const float* w   = (const float*)d_in[2];
    const float* v   = (const float*)d_in[3];
    const float* b   = (const float*)d_in[4];
    const float* w0  = (const float*)d_in[5];
    const float* b0  = (const float*)d_in[6];
    const float* w1  = (const float*)d_in[7];
    const float* b1  = (const float*)d_in[8];
    const float* w2  = (const float*)d_in[9];
    const float* b2  = (const float*)d_in[10];
    float* out = (float*)d_out;

    dim3 grid(NFM_B / TR);   // 512 blocks
    dim3 block(256);
    hipLaunchKernelGGL(nfm_fused_kernel, grid, block, 0, stream,
                       feat_ids, feat_vals, w, v, b,
                       w0, b0, w1, b1, w2, b2, out);
}

// Round 3
// 141.199 us; speedup vs baseline: 1.7318x; 1.2243x over previous
//
#include <hip/hip_runtime.h>
#include <math.h>

#define NFM_B 16384
#define NFM_F 39
#define NFM_E 16
#define NFM_H 200
#define TR    16          // rows per block -> M = one 16x16 MFMA tile
#define KPAD  232         // padded K row stride (shorts); 464B, 16B-aligned, bank-quad spread
#define NT    13          // n-tiles of 16 (208 >= 200)

typedef short short8  __attribute__((ext_vector_type(8)));   // 8 bf16 = 4 VGPRs
typedef float floatx4 __attribute__((ext_vector_type(4)));

__device__ __forceinline__ short f2bf(float x) {   // fp32 -> bf16 RNE
    union { float f; unsigned u; } a; a.f = x;
    unsigned r = a.u + 0x7FFF + ((a.u >> 16) & 1);
    return (short)(r >> 16);
}

// ws fragment layout (shorts):
//   frag idx ((tile*KS + ks)*64 + lane)*8 + j  holds  W[k][n] as bf16
//   with k = ks*32 + (lane>>4)*8 + j,  n = tile*16 + (lane&15), 0 if OOB.
#define W0F_OFF 0
#define W0F_SZ  (NT * 1 * 64 * 8)          // 6656
#define W1F_OFF (W0F_OFF + W0F_SZ)
#define W1F_SZ  (NT * 7 * 64 * 8)          // 46592
#define W2F_OFF (W1F_OFF + W1F_SZ)
#define W2F_SZ  (NT * 7 * 64 * 8)
#define WS_TOTAL (W2F_OFF + W2F_SZ)        // 99840 shorts = 199680 B

__global__ __launch_bounds__(256)
void nfm_prep_kernel(const float* __restrict__ w0,
                     const float* __restrict__ w1,
                     const float* __restrict__ w2,
                     short* __restrict__ ws)
{
    const int idx = blockIdx.x * 256 + threadIdx.x;
    if (idx >= WS_TOTAL) return;
    float val;
    if (idx < W1F_OFF) {
        const int rem = idx;
        const int j = rem & 7, lane = (rem >> 3) & 63, tile = rem >> 9;
        const int k = (lane >> 4) * 8 + j;
        const int n = tile * 16 + (lane & 15);
        val = (k < NFM_E && n < NFM_H) ? w0[k * NFM_H + n] : 0.f;
    } else if (idx < W2F_OFF) {
        const int rem = idx - W1F_OFF;
        const int j = rem & 7, lane = (rem >> 3) & 63;
        const int kt = rem >> 9;
        const int ks = kt % 7, tile = kt / 7;
        const int k = ks * 32 + (lane >> 4) * 8 + j;
        const int n = tile * 16 + (lane & 15);
        val = (k < NFM_H && n < NFM_H) ? w1[k * NFM_H + n] : 0.f;
    } else {
        const int rem = idx - W2F_OFF;
        const int j = rem & 7, lane = (rem >> 3) & 63;
        const int kt = rem >> 9;
        const int ks = kt % 7, tile = kt / 7;
        const int k = ks * 32 + (lane >> 4) * 8 + j;
        const int n = tile * 16 + (lane & 15);
        val = (k < NFM_H && n < NFM_H) ? w2[k * NFM_H + n] : 0.f;
    }
    ws[idx] = f2bf(val);
}

__global__ __launch_bounds__(256, 4)
void nfm_main_kernel(
    const int*   __restrict__ feat_ids,   // [B,F]
    const float* __restrict__ feat_vals,  // [B,F]
    const float* __restrict__ w,          // [VOCAB,1]
    const float* __restrict__ v,          // [VOCAB,E]
    const float* __restrict__ bglob,      // [1]
    const float* __restrict__ b0,
    const float* __restrict__ b1,
    const float* __restrict__ b2,
    const short* __restrict__ ws,         // bf16 weight fragments
    float* __restrict__ out)              // [B]
{
    __shared__ __attribute__((aligned(16))) short hbfA[TR * KPAD]; // 7424 B
    __shared__ __attribute__((aligned(16))) short hbfB[TR * KPAD];
    __shared__ int   idsS [TR * NFM_F];
    __shared__ float valsS[TR * NFM_F];
    __shared__ float rowsumW[4][TR];
    __shared__ float lrS[TR];

    const int tid  = threadIdx.x;
    const int row0 = blockIdx.x * TR;
    const int lane = tid & 63;
    const int wv   = tid >> 6;     // wave 0..3
    const int lq   = lane >> 4;    // quad 0..3
    const int ln   = lane & 15;

    // Zero the K-pad region (k=200..231) of both buffers (LDS is uninit; B-frag
    // zeros guarantee zero *products* only if A-pad is finite -> make it 0).
    for (int i = tid; i < 2 * TR * 32; i += 256) {
        const int buf = i >> 9;            // 0: hbfA, 1: hbfB
        const int j   = i & 511;
        const int r   = j >> 5, c = j & 31;
        (buf ? hbfB : hbfA)[r * KPAD + NFM_H + c] = 0;
    }
    // Stage ids/vals (coalesced)
    for (int i = tid; i < TR * NFM_F; i += 256) {
        idsS [i] = feat_ids [row0 * NFM_F + i];
        valsS[i] = feat_vals[row0 * NFM_F + i];
    }
    __syncthreads();

    // ---------- gather + FM pooling + LR: 16 lanes per row ----------
    {
        const int lane_e = tid & 15;
        const int r      = tid >> 4;       // 0..15
        const int*   ids = idsS  + r * NFM_F;
        const float* vls = valsS + r * NFM_F;
        float xv = 0.f, x2v2 = 0.f;
        for (int f = 0; f < NFM_F; ++f) {
            float ve = v[ids[f] * NFM_E + lane_e];   // 64B line per (row,field)
            float t  = vls[f] * ve;
            xv += t; x2v2 += t * t;
        }
        const float fm = 0.5f * (xv * xv - x2v2);
        hbfB[r * KPAD + lane_e]      = f2bf(fm);
        hbfB[r * KPAD + 16 + lane_e] = 0;            // pad k=16..31 for L0
        float lr = 0.f;
        for (int f = lane_e; f < NFM_F; f += 16)
            lr += vls[f] * w[ids[f]];
#pragma unroll
        for (int off = 8; off >= 1; off >>= 1)
            lr += __shfl_xor(lr, off, 16);
        if (lane_e == 0) lrS[r] = lr;
    }
    __syncthreads();

    // ---------- L0: fm(bf16, K=32) @ W0f -> hbfA ----------
    {
        const short8 af = *(const short8*)&hbfB[ln * KPAD + lq * 8]; // A[m=ln][k=lq*8+j]
        const short* Wf = ws + W0F_OFF;
        for (int t = wv; t < NT; t += 4) {
            const int n = t * 16 + ln;
            const float bj = (n < NFM_H) ? b0[n] : 0.f;
            floatx4 acc = {bj, bj, bj, bj};
            const short8 bf = *(const short8*)&Wf[(t * 64 + lane) * 8];
            acc = __builtin_amdgcn_mfma_f32_16x16x32_bf16(af, bf, acc, 0, 0, 0);
#pragma unroll
            for (int rg = 0; rg < 4; ++rg)          // n>=200 computes exact 0
                hbfA[(lq * 4 + rg) * KPAD + n] = f2bf(fmaxf(acc[rg], 0.f));
        }
    }
    __syncthreads();

    // ---------- L1: hbfA @ W1f -> hbfB ----------
    {
        short8 af[7];
#pragma unroll
        for (int ks = 0; ks < 7; ++ks)
            af[ks] = *(const short8*)&hbfA[ln * KPAD + ks * 32 + lq * 8];
        const short* Wf = ws + W1F_OFF;
        for (int t = wv; t < NT; t += 4) {
            const int n = t * 16 + ln;
            const float bj = (n < NFM_H) ? b1[n] : 0.f;
            floatx4 acc = {bj, bj, bj, bj};
#pragma unroll
            for (int ks = 0; ks < 7; ++ks) {
                const short8 bf = *(const short8*)&Wf[((t * 7 + ks) * 64 + lane) * 8];
                acc = __builtin_amdgcn_mfma_f32_16x16x32_bf16(af[ks], bf, acc, 0, 0, 0);
            }
#pragma unroll
            for (int rg = 0; rg < 4; ++rg)
                hbfB[(lq * 4 + rg) * KPAD + n] = f2bf(fmaxf(acc[rg], 0.f));
        }
    }
    __syncthreads();

    // ---------- L2: hbfB @ W2f -> row sums (no materialization) ----------
    {
        short8 af[7];
#pragma unroll
        for (int ks = 0; ks < 7; ++ks)
            af[ks] = *(const short8*)&hbfB[ln * KPAD + ks * 32 + lq * 8];
        const short* Wf = ws + W2F_OFF;
        float rs[4] = {0.f, 0.f, 0.f, 0.f};
        for (int t = wv; t < NT; t += 4) {
            const int n = t * 16 + ln;
            const float bj = (n < NFM_H) ? b2[n] : 0.f;
            floatx4 acc = {bj, bj, bj, bj};
#pragma unroll
            for (int ks = 0; ks < 7; ++ks) {
                const short8 bf = *(const short8*)&Wf[((t * 7 + ks) * 64 + lane) * 8];
                acc = __builtin_amdgcn_mfma_f32_16x16x32_bf16(af[ks], bf, acc, 0, 0, 0);
            }
#pragma unroll
            for (int rg = 0; rg < 4; ++rg)
                rs[rg] += fmaxf(acc[rg], 0.f);       // n>=200 adds exact 0
        }
#pragma unroll
        for (int off = 8; off >= 1; off >>= 1)
#pragma unroll
            for (int rg = 0; rg < 4; ++rg)
                rs[rg] += __shfl_xor(rs[rg], off, 16);
        if (ln == 0)
#pragma unroll
            for (int rg = 0; rg < 4; ++rg)
                rowsumW[wv][lq * 4 + rg] = rs[rg];
    }
    __syncthreads();

    // ---------- epilogue ----------
    if (tid < TR) {
        const float s = rowsumW[0][tid] + rowsumW[1][tid]
                      + rowsumW[2][tid] + rowsumW[3][tid];
        const float logit = lrS[tid] + bglob[0] + s;
        out[row0 + tid] = 1.f / (1.f + expf(-logit));
    }
}

extern "C" void kernel_launch(void* const* d_in, const int* in_sizes, int n_in,
                              void* d_out, int out_size, void* d_ws, size_t ws_size,
                              hipStream_t stream) {
    const int*   feat_ids  = (const int*)  d_in[0];
    const float* feat_vals = (const float*)d_in[1];
    const float* w   = (const float*)d_in[2];
    const float* v   = (const float*)d_in[3];
    const float* b   = (const float*)d_in[4];
    const float* w0  = (const float*)d_in[5];
    const float* b0  = (const float*)d_in[6];
    const float* w1  = (const float*)d_in[7];
    const float* b1  = (const float*)d_in[8];
    const float* w2  = (const float*)d_in[9];
    const float* b2  = (const float*)d_in[10];
    float* out = (float*)d_out;
    short* ws  = (short*)d_ws;   // needs 199680 B

    hipLaunchKernelGGL(nfm_prep_kernel, dim3((WS_TOTAL + 255) / 256), dim3(256),
                       0, stream, w0, w1, w2, ws);
    hipLaunchKernelGGL(nfm_main_kernel, dim3(NFM_B / TR), dim3(256), 0, stream,
                       feat_ids, feat_vals, w, v, b, b0, b1, b2, ws, out);
}